// Round 1
// baseline (772.815 us; speedup 1.0000x reference)
//
#include <hip/hip_runtime.h>

namespace {

constexpr int B_   = 4;
constexpr int CIN  = 64;
constexpr int COUT = 128;
constexpr int HIN  = 64,  WIN  = 1024;
constexpr int HOUT = 32,  WOUT = 512;
constexpr int TW   = 16;     // wo positions per block
constexpr int AP   = 1025;   // A p-stride in words (bank spread)
constexpr int KCH  = 16;     // Wc k-chunk staged per tile
constexpr int WCP  = 132;    // WcT kk-stride in words (mult of 4 for b128 align)

__global__ __launch_bounds__(256, 2)
void fused_ccconv(const float* __restrict__ x,  const float* __restrict__ r,
                  const float* __restrict__ W1, const float* __restrict__ b1,
                  const float* __restrict__ W2, const float* __restrict__ b2,
                  const float* __restrict__ Wc, const float* __restrict__ bc,
                  float* __restrict__ out)
{
    __shared__ float A[TW * AP];        // A[p][k], k = c*16 + i*4 + j
    __shared__ float WcT[KCH * WCP];    // WcT[kk][o]

    const int t   = threadIdx.x;
    const int bx  = blockIdx.x;
    const int wt  = bx & 31;            // wo tile (32 tiles)
    const int ho  = (bx >> 5) & 31;
    const int b   = bx >> 10;
    const int wo0 = wt * TW;

    const float* rb = r + (size_t)b * HIN * WIN;

    // ---- output 1: r_center = r[b, 2ho+1, 2wo+1] ----
    if (t < TW) {
        const int wo = wo0 + t;
        out[(size_t)B_*COUT*HOUT*WOUT + ((size_t)b*HOUT + ho)*WOUT + wo] =
            rb[(2*ho + 1)*WIN + (2*wo + 1)];
    }

    // ---- phase 1: per-(position,tap) MLP -> A = w * x_patch ----
    {
        const int p   = t >> 4;
        const int tap = t & 15;
        const int i   = tap >> 2;       // kw index (dim 4 of unfold)
        const int j   = tap & 3;        // kh index (dim 5 of unfold)
        const int wo  = wo0 + p;

        const float AZI = 0.006135923151542565f;  // 2*pi/1024
        const float INC = 0.0073f;
        const float di = (float)(i - 2);
        const float dj = (float)(j - 2);
        const float cA = cosf(AZI * dj), sA = sinf(AZI * dj);  // depend on j
        const float cI = cosf(INC * di), sI = sinf(INC * di);  // depend on i

        // padded coords: h wraps, w const-pads
        const int hsrc = (2*ho + j + 63) & 63;    // (2ho+j-1) mod 64
        const int wsrc = 2*wo + i - 1;
        const bool inb = (unsigned)wsrc < (unsigned)WIN;

        const float rpv = inb ? rb[hsrc*WIN + wsrc] : 100.0f;
        const float rc  = rb[(2*ho + 1)*WIN + (2*wo + 1)];

        const float pe0 = rpv * cA * cI - rc;
        const float pe1 = rpv * cA * sI;
        const float pe2 = rpv * sA;

        float w[CIN];
        #pragma unroll
        for (int c = 0; c < CIN; ++c) w[c] = b2[c];

        // h computed on the fly; W1/W2 indices wave-uniform -> scalar loads
        for (int c1 = 0; c1 < CIN; ++c1) {
            float hv = fmaf(pe0, W1[c1],
                       fmaf(pe1, W1[CIN + c1],
                       fmaf(pe2, W1[2*CIN + c1], b1[c1])));
            hv = (hv >= 0.0f) ? hv : 0.2f * hv;   // leaky_relu 0.2
            const float* w2r = W2 + c1 * CIN;
            #pragma unroll
            for (int c = 0; c < CIN; ++c) w[c] = fmaf(hv, w2r[c], w[c]);
        }

        // A[p][c*16 + tap] = w[c] * x_patch (x: zero-pad in w, wrap in h)
        const float* xb = x + (size_t)b*CIN*HIN*WIN + hsrc*WIN + wsrc;
        float* Arow = A + p*AP + tap;
        #pragma unroll
        for (int c = 0; c < CIN; ++c) {
            const float xv = inb ? xb[(size_t)c * HIN * WIN] : 0.0f;
            Arow[c * 16] = w[c] * xv;
        }
    }

    // ---- phase 2: out[p][o] = bc[o] + sum_k A[p][k] * Wc[o][k] ----
    const int og = t & 31;      // 4 consecutive o
    const int pg = t >> 5;      // 2 consecutive p
    const int o0 = og * 4;
    const int p0 = pg * 2;

    float acc[2][4] = {{0.f,0.f,0.f,0.f},{0.f,0.f,0.f,0.f}};

    for (int k0 = 0; k0 < CIN*16; k0 += KCH) {
        __syncthreads();   // also guards A writes before first reads
        {
            // stage Wc[0:128][k0:k0+16] transposed; 8 floats per thread
            const int o   = t >> 1;
            const int kk0 = (t & 1) * 8;
            const float4* src = reinterpret_cast<const float4*>(
                Wc + (size_t)o*(CIN*16) + k0 + kk0);
            #pragma unroll
            for (int q = 0; q < 2; ++q) {
                const float4 v = src[q];
                const int kk = kk0 + 4*q;
                WcT[(kk+0)*WCP + o] = v.x;
                WcT[(kk+1)*WCP + o] = v.y;
                WcT[(kk+2)*WCP + o] = v.z;
                WcT[(kk+3)*WCP + o] = v.w;
            }
        }
        __syncthreads();
        #pragma unroll
        for (int kk = 0; kk < KCH; ++kk) {
            const int k = k0 + kk;
            const float4 wc4 = *reinterpret_cast<const float4*>(&WcT[kk*WCP + o0]);
            const float a0 = A[p0*AP + k];          // broadcast within half-wave
            const float a1 = A[(p0+1)*AP + k];
            acc[0][0] = fmaf(wc4.x, a0, acc[0][0]);
            acc[0][1] = fmaf(wc4.y, a0, acc[0][1]);
            acc[0][2] = fmaf(wc4.z, a0, acc[0][2]);
            acc[0][3] = fmaf(wc4.w, a0, acc[0][3]);
            acc[1][0] = fmaf(wc4.x, a1, acc[1][0]);
            acc[1][1] = fmaf(wc4.y, a1, acc[1][1]);
            acc[1][2] = fmaf(wc4.z, a1, acc[1][2]);
            acc[1][3] = fmaf(wc4.w, a1, acc[1][3]);
        }
    }

    #pragma unroll
    for (int q = 0; q < 4; ++q) {
        const float bco = bc[o0 + q];
        #pragma unroll
        for (int pp = 0; pp < 2; ++pp) {
            out[(((size_t)b*COUT + o0 + q)*HOUT + ho)*WOUT + wo0 + p0 + pp] =
                acc[pp][q] + bco;
        }
    }
}

} // namespace

extern "C" void kernel_launch(void* const* d_in, const int* in_sizes, int n_in,
                              void* d_out, int out_size, void* d_ws, size_t ws_size,
                              hipStream_t stream) {
    const float* x  = (const float*)d_in[0];
    const float* r  = (const float*)d_in[1];
    const float* W1 = (const float*)d_in[2];
    const float* b1 = (const float*)d_in[3];
    const float* W2 = (const float*)d_in[4];
    const float* b2 = (const float*)d_in[5];
    const float* Wc = (const float*)d_in[6];
    const float* bc = (const float*)d_in[7];
    float* out = (float*)d_out;

    dim3 grid(B_ * HOUT * (WOUT / TW));   // 4*32*32 = 4096
    dim3 block(256);
    hipLaunchKernelGGL(fused_ccconv, grid, block, 0, stream,
                       x, r, W1, b1, W2, b2, Wc, bc, out);
}

// Round 2
// 342.498 us; speedup vs baseline: 2.2564x; 2.2564x over previous
//
#include <hip/hip_runtime.h>
#include <hip/hip_bf16.h>

namespace {

constexpr int B_   = 4;
constexpr int CIN  = 64;
constexpr int COUT = 128;
constexpr int HIN  = 64,  WIN  = 1024;
constexpr int HOUT = 32,  WOUT = 512;
constexpr int TW   = 16;     // wo positions per block
constexpr int AB   = 1032;   // A row stride in bf16 elems (2064 B = 16 B mod 128 -> conflict-free b128)
constexpr int KTOT = CIN * 16;  // 1024

typedef __bf16 bf16x8 __attribute__((ext_vector_type(8)));
typedef float  f32x4  __attribute__((ext_vector_type(4)));

__global__ void cvt_wc(const float* __restrict__ Wc, __hip_bfloat16* __restrict__ wcb, int n) {
    int i = blockIdx.x * 256 + threadIdx.x;
    if (i < n) wcb[i] = __float2bfloat16(Wc[i]);
}

__global__ __launch_bounds__(256, 4)
void fused_ccconv(const float* __restrict__ x,  const float* __restrict__ r,
                  const float* __restrict__ W1, const float* __restrict__ b1,
                  const float* __restrict__ W2, const float* __restrict__ b2,
                  const __hip_bfloat16* __restrict__ WcB,
                  const float* __restrict__ bc,
                  float* __restrict__ out)
{
    __shared__ __hip_bfloat16 A[TW * AB];   // A[p][k] bf16, k = c*16 + i*4 + j

    const int t   = threadIdx.x;
    const int bx  = blockIdx.x;
    const int wt  = bx & 31;            // wo tile (32 tiles)
    const int ho  = (bx >> 5) & 31;
    const int b   = bx >> 10;
    const int wo0 = wt * TW;

    const float* rb = r + (size_t)b * HIN * WIN;

    // ---- output 1: r_center ----
    if (t < TW) {
        const int wo = wo0 + t;
        out[(size_t)B_*COUT*HOUT*WOUT + ((size_t)b*HOUT + ho)*WOUT + wo] =
            rb[(2*ho + 1)*WIN + (2*wo + 1)];
    }

    // ---- phase 1: per-(position,tap) MLP -> A[p][k] = w[c] * x_patch (bf16) ----
    {
        const int p   = t >> 4;
        const int tap = t & 15;
        const int i   = tap >> 2;       // kw index
        const int j   = tap & 3;        // kh index
        const int wo  = wo0 + p;

        const float AZI = 0.006135923151542565f;  // 2*pi/1024
        const float INC = 0.0073f;
        const float di = (float)(i - 2);
        const float dj = (float)(j - 2);
        const float cA = cosf(AZI * dj), sA = sinf(AZI * dj);
        const float cI = cosf(INC * di), sI = sinf(INC * di);

        const int hsrc = (2*ho + j + 63) & 63;    // wrap pad in H
        const int wsrc = 2*wo + i - 1;            // const pad in W
        const bool inb = (unsigned)wsrc < (unsigned)WIN;

        const float rpv = inb ? rb[hsrc*WIN + wsrc] : 100.0f;
        const float rc  = rb[(2*ho + 1)*WIN + (2*wo + 1)];

        const float pe0 = rpv * cA * cI - rc;
        const float pe1 = rpv * cA * sI;
        const float pe2 = rpv * sA;

        float w[CIN];
        #pragma unroll
        for (int c = 0; c < CIN; ++c) w[c] = b2[c];

        for (int c1 = 0; c1 < CIN; ++c1) {
            float hv = fmaf(pe0, W1[c1],
                       fmaf(pe1, W1[CIN + c1],
                       fmaf(pe2, W1[2*CIN + c1], b1[c1])));
            hv = (hv >= 0.0f) ? hv : 0.2f * hv;
            const float* w2r = W2 + c1 * CIN;
            #pragma unroll
            for (int c = 0; c < CIN; ++c) w[c] = fmaf(hv, w2r[c], w[c]);
        }

        const float* xb = x + (size_t)b*CIN*HIN*WIN + hsrc*WIN + wsrc;
        __hip_bfloat16* Arow = A + p*AB + tap;
        #pragma unroll
        for (int c = 0; c < CIN; ++c) {
            const float xv = inb ? xb[(size_t)c * HIN * WIN] : 0.0f;
            Arow[c * 16] = __float2bfloat16(w[c] * xv);
        }
    }

    __syncthreads();

    // ---- phase 2: MFMA  D[o][p] = sum_k Wc[o][k] * A[p][k] ----
    // wave wv handles o-tiles [wv*32, wv*32+16) and [wv*32+16, wv*32+32)
    const int wv   = t >> 6;
    const int ln   = t & 63;
    const int pcol = ln & 15;       // n  (= p position)
    const int quad = ln >> 4;       // k-quad / m-row group

    const int o0 = wv * 32;

    // A-operand (Wc): lane holds Wc[o0 + (ln&15)][k0 + quad*8 .. +7]
    const __hip_bfloat16* wcP0 = WcB + ((size_t)(o0 + pcol)) * KTOT + quad*8;
    const __hip_bfloat16* wcP1 = wcP0 + (size_t)16 * KTOT;
    // B-operand (A): lane holds A[pcol][k0 + quad*8 .. +7]
    const __hip_bfloat16* aP   = A + pcol*AB + quad*8;

    f32x4 acc0 = {0.f,0.f,0.f,0.f};
    f32x4 acc1 = {0.f,0.f,0.f,0.f};

    #pragma unroll 4
    for (int ks = 0; ks < KTOT/32; ++ks) {
        const bf16x8 af = *reinterpret_cast<const bf16x8*>(aP   + ks*32);
        const bf16x8 w0 = *reinterpret_cast<const bf16x8*>(wcP0 + ks*32);
        const bf16x8 w1 = *reinterpret_cast<const bf16x8*>(wcP1 + ks*32);
        acc0 = __builtin_amdgcn_mfma_f32_16x16x32_bf16(w0, af, acc0, 0, 0, 0);
        acc1 = __builtin_amdgcn_mfma_f32_16x16x32_bf16(w1, af, acc1, 0, 0, 0);
    }

    // D layout: row (=o within tile) = quad*4 + q, col (=p) = pcol -> coalesced stores
    #pragma unroll
    for (int q = 0; q < 4; ++q) {
        const int oa = o0 + quad*4 + q;
        const int ob = oa + 16;
        out[(((size_t)b*COUT + oa)*HOUT + ho)*WOUT + wo0 + pcol] = acc0[q] + bc[oa];
        out[(((size_t)b*COUT + ob)*HOUT + ho)*WOUT + wo0 + pcol] = acc1[q] + bc[ob];
    }
}

} // namespace

extern "C" void kernel_launch(void* const* d_in, const int* in_sizes, int n_in,
                              void* d_out, int out_size, void* d_ws, size_t ws_size,
                              hipStream_t stream) {
    const float* x  = (const float*)d_in[0];
    const float* r  = (const float*)d_in[1];
    const float* W1 = (const float*)d_in[2];
    const float* b1 = (const float*)d_in[3];
    const float* W2 = (const float*)d_in[4];
    const float* b2 = (const float*)d_in[5];
    const float* Wc = (const float*)d_in[6];
    const float* bc = (const float*)d_in[7];
    float* out = (float*)d_out;

    __hip_bfloat16* wcb = (__hip_bfloat16*)d_ws;   // 128*1024 bf16 = 256 KB
    const int nwc = COUT * KTOT;

    hipLaunchKernelGGL(cvt_wc, dim3((nwc + 255)/256), dim3(256), 0, stream, Wc, wcb, nwc);

    dim3 grid(B_ * HOUT * (WOUT / TW));   // 4096
    dim3 block(256);
    hipLaunchKernelGGL(fused_ccconv, grid, block, 0, stream,
                       x, r, W1, b1, W2, b2, wcb, bc, out);
}

// Round 3
// 289.211 us; speedup vs baseline: 2.6722x; 1.1842x over previous
//
#include <hip/hip_runtime.h>
#include <hip/hip_bf16.h>

namespace {

constexpr int B_   = 4;
constexpr int CIN  = 64;
constexpr int COUT = 128;
constexpr int HIN  = 64,  WIN  = 1024;
constexpr int HOUT = 32,  WOUT = 512;
constexpr int TW   = 16;        // wo positions per block
constexpr int SP   = 1096;      // per-position S stride in bf16 elems (2192 B: mult16, !=0 mod 128)
constexpr int KTOT = CIN * 16;  // 1024

typedef __bf16 bf16x8 __attribute__((ext_vector_type(8)));
typedef float  f32x4  __attribute__((ext_vector_type(4)));

// wcb[o][tap*64+c] = Wc[o][c*16+tap] (bf16);  w2t[c][c1] = W2[c1][c] (bf16)
__global__ void cvt_wts(const float* __restrict__ Wc, const float* __restrict__ W2,
                        __hip_bfloat16* __restrict__ wcb, __hip_bfloat16* __restrict__ w2t) {
    int i = blockIdx.x * 256 + threadIdx.x;
    if (i < COUT * KTOT) {
        int o = i >> 10, k = i & 1023, tap = k >> 6, c = k & 63;
        wcb[i] = __float2bfloat16(Wc[(size_t)o * KTOT + c * 16 + tap]);
    } else if (i < COUT * KTOT + CIN * CIN) {
        int m = i - COUT * KTOT;
        int c = m >> 6, c1 = m & 63;
        w2t[m] = __float2bfloat16(W2[c1 * CIN + c]);
    }
}

__global__ __launch_bounds__(256, 3)
void fused_ccconv(const float* __restrict__ x,  const float* __restrict__ r,
                  const float* __restrict__ W1, const float* __restrict__ b1,
                  const __hip_bfloat16* __restrict__ W2T, const float* __restrict__ b2,
                  const __hip_bfloat16* __restrict__ WcB, const float* __restrict__ bc,
                  float* __restrict__ out)
{
    // Per position p: elems [0,1088) hold w[tap][c] (stride 68, b64-aligned) during phase 1,
    // then A[k'=tap*64+c] overwrites [0,1024) in phase 1c (same wave owns both -> in-order DS).
    __shared__ __hip_bfloat16 S[TW * SP];   // 35,072 B

    const int t   = threadIdx.x;
    const int bx  = blockIdx.x;
    const int wt  = bx & 31;
    const int ho  = (bx >> 5) & 31;
    const int b   = bx >> 10;
    const int wo0 = wt * TW;

    const float* rb = r + (size_t)b * HIN * WIN;

    // ---- output 1: r_center ----
    if (t < TW) {
        const int wo = wo0 + t;
        out[(size_t)B_*COUT*HOUT*WOUT + ((size_t)b*HOUT + ho)*WOUT + wo] =
            rb[(2*ho + 1)*WIN + (2*wo + 1)];
    }

    const int ln   = t & 63;
    const int wv   = t >> 6;
    const int lm   = ln & 15;
    const int quad = ln >> 4;

    const float AZI = 0.006135923151542565f;  // 2*pi/1024
    const float INC = 0.0073f;

    // ================= phase 1b: w = leaky(pe@W1+b1)@W2 + b2 via MFMA =================
    {
        // B-frags (W2T) from global, L1-hot: lane holds W2T[nt*16+lm][k..k+7]
        bf16x8 bfr[4][2];
        float  b2v[4];
        #pragma unroll
        for (int nt = 0; nt < 4; ++nt) {
            #pragma unroll
            for (int ks = 0; ks < 2; ++ks)
                bfr[nt][ks] = *reinterpret_cast<const bf16x8*>(
                    W2T + (nt*16 + lm)*CIN + ks*32 + quad*8);
            b2v[nt] = b2[nt*16 + lm];
        }

        // this lane's tap (A-operand row) = lm
        const int i_ = lm >> 2, j_ = lm & 3;
        const float di = (float)(i_ - 2), dj = (float)(j_ - 2);
        const float cA = cosf(AZI * dj), sA = sinf(AZI * dj);
        const float cI = cosf(INC * di), sI = sinf(INC * di);
        const int hsrc = (2*ho + j_ + 63) & 63;

        #pragma unroll
        for (int mt = 0; mt < 4; ++mt) {
            const int p  = wv*4 + mt;
            const int wo = wo0 + p;
            const int wsrc = 2*wo + i_ - 1;
            const bool inb = (unsigned)wsrc < (unsigned)WIN;
            const float rpv = inb ? rb[hsrc*WIN + wsrc] : 100.0f;
            const float rc  = rb[(2*ho + 1)*WIN + (2*wo + 1)];
            const float pe0 = rpv * cA * cI - rc;
            const float pe1 = rpv * cA * sI;
            const float pe2 = rpv * sA;

            // A-frags: lane holds h[tap=lm][c1 = ks*32 + quad*8 + j]
            bf16x8 af0, af1;
            #pragma unroll
            for (int ks = 0; ks < 2; ++ks) {
                const int cb = ks*32 + quad*8;
                #pragma unroll
                for (int j = 0; j < 8; ++j) {
                    const int c1 = cb + j;
                    float hv = fmaf(pe0, W1[c1],
                               fmaf(pe1, W1[CIN + c1],
                               fmaf(pe2, W1[2*CIN + c1], b1[c1])));
                    hv = (hv >= 0.0f) ? hv : 0.2f * hv;
                    __hip_bfloat16 hb = __float2bfloat16(hv);
                    if (ks == 0) af0[j] = *reinterpret_cast<__bf16*>(&hb);
                    else         af1[j] = *reinterpret_cast<__bf16*>(&hb);
                }
            }

            #pragma unroll
            for (int nt = 0; nt < 4; ++nt) {
                f32x4 acc = {b2v[nt], b2v[nt], b2v[nt], b2v[nt]};
                acc = __builtin_amdgcn_mfma_f32_16x16x32_bf16(af0, bfr[nt][0], acc, 0, 0, 0);
                acc = __builtin_amdgcn_mfma_f32_16x16x32_bf16(af1, bfr[nt][1], acc, 0, 0, 0);
                // D: row(tap) = quad*4+q, col(c) = nt*16+lm  -> w[tap][c], stride 68
                #pragma unroll
                for (int q = 0; q < 4; ++q)
                    S[p*SP + (quad*4 + q)*68 + nt*16 + lm] = __float2bfloat16(acc[q]);
            }
        }
    }

    // ================= phase 1c: A[p][tap*64+c] = w[tap][c] * x =================
    {
        const int p   = t >> 4;
        const int tap = t & 15;
        const int i_  = tap >> 2, j_ = tap & 3;
        const int hsrc = (2*ho + j_ + 63) & 63;
        const int wo   = wo0 + p;
        const int wsrc = 2*wo + i_ - 1;
        const bool inb = (unsigned)wsrc < (unsigned)WIN;

        // read this row's w (in-order DS => all reads precede the A-writes below)
        uint2 wrow[16];
        const uint2* wp = reinterpret_cast<const uint2*>(S + p*SP + tap*68);
        #pragma unroll
        for (int u = 0; u < 16; ++u) wrow[u] = wp[u];

        const float* xb = x + (size_t)b*CIN*HIN*WIN + hsrc*WIN + wsrc;

        // prefetch all x for deep pipelining
        float xall[CIN];
        #pragma unroll
        for (int c = 0; c < CIN; ++c)
            xall[c] = inb ? xb[(size_t)c * HIN * WIN] : 0.0f;

        uint4* Ap = reinterpret_cast<uint4*>(S + p*SP + tap*64);
        #pragma unroll
        for (int g = 0; g < 8; ++g) {
            uint pk[4];
            #pragma unroll
            for (int pr = 0; pr < 4; ++pr) {
                const int c0 = g*8 + pr*2;
                const uint2 wv2 = wrow[c0 >> 2];
                const uint word = (c0 & 2) ? wv2.y : wv2.x;
                const float w0 = __uint_as_float(word << 16);
                const float w1 = __uint_as_float(word & 0xffff0000u);
                __hip_bfloat16 p0 = __float2bfloat16(w0 * xall[c0]);
                __hip_bfloat16 p1 = __float2bfloat16(w1 * xall[c0 + 1]);
                const uint lo = *reinterpret_cast<unsigned short*>(&p0);
                const uint hi = *reinterpret_cast<unsigned short*>(&p1);
                pk[pr] = lo | (hi << 16);
            }
            Ap[g] = make_uint4(pk[0], pk[1], pk[2], pk[3]);
        }
    }

    __syncthreads();

    // ================= phase 2: out[o][p] = bc[o] + sum_k Wc[o][k']*A[p][k'] =================
    {
        const int o0 = wv * 32;
        const __hip_bfloat16* wcP0 = WcB + ((size_t)(o0 + lm)) * KTOT + quad*8;
        const __hip_bfloat16* wcP1 = wcP0 + (size_t)16 * KTOT;
        const __hip_bfloat16* aP   = S + lm*SP + quad*8;

        f32x4 acc0 = {0.f,0.f,0.f,0.f};
        f32x4 acc1 = {0.f,0.f,0.f,0.f};

        #pragma unroll 4
        for (int ks = 0; ks < KTOT/32; ++ks) {
            const bf16x8 af = *reinterpret_cast<const bf16x8*>(aP   + ks*32);
            const bf16x8 w0 = *reinterpret_cast<const bf16x8*>(wcP0 + ks*32);
            const bf16x8 w1 = *reinterpret_cast<const bf16x8*>(wcP1 + ks*32);
            acc0 = __builtin_amdgcn_mfma_f32_16x16x32_bf16(w0, af, acc0, 0, 0, 0);
            acc1 = __builtin_amdgcn_mfma_f32_16x16x32_bf16(w1, af, acc1, 0, 0, 0);
        }

        #pragma unroll
        for (int q = 0; q < 4; ++q) {
            const int oa = o0 + quad*4 + q;
            const int ob = oa + 16;
            out[(((size_t)b*COUT + oa)*HOUT + ho)*WOUT + wo0 + lm] = acc0[q] + bc[oa];
            out[(((size_t)b*COUT + ob)*HOUT + ho)*WOUT + wo0 + lm] = acc1[q] + bc[ob];
        }
    }
}

} // namespace

extern "C" void kernel_launch(void* const* d_in, const int* in_sizes, int n_in,
                              void* d_out, int out_size, void* d_ws, size_t ws_size,
                              hipStream_t stream) {
    const float* x  = (const float*)d_in[0];
    const float* r  = (const float*)d_in[1];
    const float* W1 = (const float*)d_in[2];
    const float* b1 = (const float*)d_in[3];
    const float* W2 = (const float*)d_in[4];
    const float* b2 = (const float*)d_in[5];
    const float* Wc = (const float*)d_in[6];
    const float* bc = (const float*)d_in[7];
    float* out = (float*)d_out;

    __hip_bfloat16* wcb = (__hip_bfloat16*)d_ws;                       // 256 KB
    __hip_bfloat16* w2t = (__hip_bfloat16*)((char*)d_ws + 262144);     // 8 KB

    const int ntot = COUT*KTOT + CIN*CIN;   // 135168
    hipLaunchKernelGGL(cvt_wts, dim3((ntot + 255)/256), dim3(256), 0, stream,
                       Wc, W2, wcb, w2t);

    dim3 grid(B_ * HOUT * (WOUT / TW));   // 4096
    dim3 block(256);
    hipLaunchKernelGGL(fused_ccconv, grid, block, 0, stream,
                       x, r, W1, b1, w2t, b2, wcb, bc, out);
}